// Round 1
// baseline (2553.743 us; speedup 1.0000x reference)
//
#include <hip/hip_runtime.h>
#include <stdint.h>
#include <stddef.h>

#define N_ 8
#define T_ 512
#define C_ 1024
#define H_ 256
#define V_ 32000
#define CW 32      // columns per chunk

// workspace byte offsets
#define OFF_START   0u
#define OFF_LSE     4096u
#define OFF_EVP     8192u        // 8 f32 per-seq evidence
#define OFF_EA      16384u       // 2*8*1024 tagged u32 = 64KB (memset 0 each launch)
#define OFF_FT      81920u       // 1024*256 f32 = 1MB
#define OFF_P       1130496u     // 1024*1024 f32 = 4MB
#define OFF_PART    5324800u     // 1024*16 f32 partials
#define OFF_EEXP    5849088u     // 4096*1024 f32 = 16MB

typedef __attribute__((ext_vector_type(8))) short short8;
typedef __attribute__((ext_vector_type(4))) float floatx4;

__device__ __forceinline__ float dot4(float4 a, float4 b) {
  return a.x*b.x + a.y*b.y + a.z*b.z + a.w*b.w;
}

__device__ __forceinline__ unsigned short f2bf(float f) {
  unsigned u = __float_as_uint(f);
  unsigned r = u + 0x7fffu + ((u >> 16) & 1u);   // round-to-nearest-even
  return (unsigned short)(r >> 16);
}

__device__ __forceinline__ unsigned pk_bf2(float x, float y) {
  return ((unsigned)f2bf(y) << 16) | (unsigned)f2bf(x);
}

__device__ __forceinline__ short8 pack8(float4 a, float4 b) {
  union { short8 s; unsigned u[4]; } r;
  r.u[0] = pk_bf2(a.x, a.y);
  r.u[1] = pk_bf2(a.z, a.w);
  r.u[2] = pk_bf2(b.x, b.y);
  r.u[3] = pk_bf2(b.z, b.w);
  return r.s;
}

// ---------------------------------------------------------------- K1: start distribution
__global__ __launch_bounds__(256) void k_start(
    const float* __restrict__ se, const float* __restrict__ lw, const float* __restrict__ lb,
    const float* __restrict__ W1, const float* __restrict__ b1,
    const float* __restrict__ W2, const float* __restrict__ b2,
    const float* __restrict__ nse, float* __restrict__ out_start)
{
  __shared__ float xs[H_], fx[H_], h1[H_];
  __shared__ float lg[C_];
  __shared__ float redk[4];
  int tid = threadIdx.x;
  xs[tid] = se[tid];
  __syncthreads();
  {
    float acc = lb[tid];
    const float4* wr = (const float4*)(lw + (size_t)tid*H_);
    for (int k = 0; k < H_/4; ++k) acc += dot4(wr[k], *(const float4*)&xs[k*4]);
    fx[tid] = acc;
  }
  __syncthreads();
  for (int L = 0; L < 2; ++L) {
    {
      float acc = b1[L*H_ + tid];
      const float4* wr = (const float4*)(W1 + (size_t)(L*H_ + tid)*H_);
      for (int k = 0; k < H_/4; ++k) acc += dot4(wr[k], *(const float4*)&fx[k*4]);
      h1[tid] = fmaxf(acc, 0.f);
    }
    __syncthreads();
    {
      float acc = b2[L*H_ + tid];
      const float4* wr = (const float4*)(W2 + (size_t)(L*H_ + tid)*H_);
      for (int k = 0; k < H_/4; ++k) acc += dot4(wr[k], *(const float4*)&h1[k*4]);
      fx[tid] += fmaxf(acc, 0.f);
    }
    __syncthreads();
  }
  float lmax = -1e30f;
  for (int r = 0; r < 4; ++r) {
    int cc = tid + r*256;
    float acc = 0.f;
    const float4* er = (const float4*)(nse + (size_t)cc*H_);
    for (int k = 0; k < H_/4; ++k) acc += dot4(er[k], *(const float4*)&fx[k*4]);
    lg[cc] = acc;
    lmax = fmaxf(lmax, acc);
  }
  for (int m = 32; m; m >>= 1) lmax = fmaxf(lmax, __shfl_xor(lmax, m, 64));
  if ((tid & 63) == 0) redk[tid >> 6] = lmax;
  __syncthreads();
  float M = fmaxf(fmaxf(redk[0], redk[1]), fmaxf(redk[2], redk[3]));
  __syncthreads();
  float ssum = 0.f;
  for (int r = 0; r < 4; ++r) ssum += __expf(lg[tid + r*256] - M);
  for (int m = 32; m; m >>= 1) ssum += __shfl_xor(ssum, m, 64);
  if ((tid & 63) == 0) redk[tid >> 6] = ssum;
  __syncthreads();
  float S = redk[0] + redk[1] + redk[2] + redk[3];
  float lse = M + __logf(S);
  for (int r = 0; r < 4; ++r) {
    int cc = tid + r*256;
    out_start[cc] = lg[cc] - lse;
  }
}

// ---------------------------------------------------------------- K2: transition logits GEMM (f32)
__global__ __launch_bounds__(256) void k_gemm_cc(
    const float* __restrict__ A, const float* __restrict__ B, float* __restrict__ Cout)
{
  __shared__ float As[64][69];
  __shared__ float Bs[64][69];
  int tid = threadIdx.x;
  int bi = blockIdx.y, bj = blockIdx.x;
  int sr = tid >> 2, sq = tid & 3;
  int tx = tid & 15, ty = tid >> 4;
  float acc[4][4] = {};
  for (int kb = 0; kb < H_; kb += 64) {
    __syncthreads();
    {
      const float* ar = A + (size_t)(bi*64 + sr)*H_ + kb + sq*16;
      const float* br = B + (size_t)(bj*64 + sr)*H_ + kb + sq*16;
#pragma unroll
      for (int qq = 0; qq < 4; ++qq) {
        float4 av = *(const float4*)(ar + qq*4);
        float4 bv = *(const float4*)(br + qq*4);
        int kk = sq*16 + qq*4;
        As[sr][kk+0]=av.x; As[sr][kk+1]=av.y; As[sr][kk+2]=av.z; As[sr][kk+3]=av.w;
        Bs[sr][kk+0]=bv.x; Bs[sr][kk+1]=bv.y; Bs[sr][kk+2]=bv.z; Bs[sr][kk+3]=bv.w;
      }
    }
    __syncthreads();
#pragma unroll 4
    for (int k = 0; k < 64; ++k) {
      float a0 = As[ty*4+0][k], a1 = As[ty*4+1][k], a2 = As[ty*4+2][k], a3 = As[ty*4+3][k];
      float b0 = Bs[tx*4+0][k], b1 = Bs[tx*4+1][k], b2 = Bs[tx*4+2][k], b3 = Bs[tx*4+3][k];
      acc[0][0]+=a0*b0; acc[0][1]+=a0*b1; acc[0][2]+=a0*b2; acc[0][3]+=a0*b3;
      acc[1][0]+=a1*b0; acc[1][1]+=a1*b1; acc[1][2]+=a1*b2; acc[1][3]+=a1*b3;
      acc[2][0]+=a2*b0; acc[2][1]+=a2*b1; acc[2][2]+=a2*b2; acc[2][3]+=a2*b3;
      acc[3][0]+=a3*b0; acc[3][1]+=a3*b1; acc[3][2]+=a3*b2; acc[3][3]+=a3*b3;
    }
  }
#pragma unroll
  for (int ii = 0; ii < 4; ++ii)
#pragma unroll
    for (int jj = 0; jj < 4; ++jj)
      Cout[(size_t)(bi*64 + ty*4 + ii)*C_ + bj*64 + tx*4 + jj] = acc[ii][jj];
}

// ---------------------------------------------------------------- K3: row softmax in place
__global__ __launch_bounds__(256) void k_softmax_rows(float* __restrict__ P)
{
  __shared__ float redk[4];
  int row = blockIdx.x, tid = threadIdx.x;
  float4* pr = (float4*)(P + (size_t)row*C_);
  float4 v = pr[tid];
  float m = fmaxf(fmaxf(v.x, v.y), fmaxf(v.z, v.w));
  for (int mm = 32; mm; mm >>= 1) m = fmaxf(m, __shfl_xor(m, mm, 64));
  if ((tid & 63) == 0) redk[tid >> 6] = m;
  __syncthreads();
  float M = fmaxf(fmaxf(redk[0], redk[1]), fmaxf(redk[2], redk[3]));
  __syncthreads();
  float4 e;
  e.x = __expf(v.x - M); e.y = __expf(v.y - M); e.z = __expf(v.z - M); e.w = __expf(v.w - M);
  float s = e.x + e.y + e.z + e.w;
  for (int mm = 32; mm; mm >>= 1) s += __shfl_xor(s, mm, 64);
  if ((tid & 63) == 0) redk[tid >> 6] = s;
  __syncthreads();
  float S = redk[0] + redk[1] + redk[2] + redk[3];
  float inv = 1.0f / S;
  e.x *= inv; e.y *= inv; e.z *= inv; e.w *= inv;
  pr[tid] = e;
}

// ---------------------------------------------------------------- K4: terminal MLP
__global__ __launch_bounds__(256) void k_mlp(
    const float* __restrict__ inp, const float* __restrict__ W1, const float* __restrict__ b1,
    const float* __restrict__ W2, const float* __restrict__ b2, float* __restrict__ ft)
{
  __shared__ float xs[4][H_];
  __shared__ float hs[4][H_];
  int tid = threadIdx.x;
  int r0 = blockIdx.x * 4;
  int lr = tid >> 6, lc = (tid & 63) * 4;
  *(float4*)&xs[lr][lc] = *(const float4*)(inp + (size_t)(r0+lr)*H_ + lc);
  __syncthreads();
  for (int L = 0; L < 2; ++L) {
    {
      const float4* wr = (const float4*)(W1 + (size_t)(L*H_ + tid)*H_);
      float bb = b1[L*H_ + tid];
      float a0=bb, a1=bb, a2=bb, a3=bb;
      for (int k = 0; k < H_/4; ++k) {
        float4 w = wr[k];
        a0 += dot4(w, *(const float4*)&xs[0][k*4]);
        a1 += dot4(w, *(const float4*)&xs[1][k*4]);
        a2 += dot4(w, *(const float4*)&xs[2][k*4]);
        a3 += dot4(w, *(const float4*)&xs[3][k*4]);
      }
      hs[0][tid]=fmaxf(a0,0.f); hs[1][tid]=fmaxf(a1,0.f);
      hs[2][tid]=fmaxf(a2,0.f); hs[3][tid]=fmaxf(a3,0.f);
    }
    __syncthreads();
    {
      const float4* wr = (const float4*)(W2 + (size_t)(L*H_ + tid)*H_);
      float bb = b2[L*H_ + tid];
      float a0=bb, a1=bb, a2=bb, a3=bb;
      for (int k = 0; k < H_/4; ++k) {
        float4 w = wr[k];
        a0 += dot4(w, *(const float4*)&hs[0][k*4]);
        a1 += dot4(w, *(const float4*)&hs[1][k*4]);
        a2 += dot4(w, *(const float4*)&hs[2][k*4]);
        a3 += dot4(w, *(const float4*)&hs[3][k*4]);
      }
      xs[0][tid] += fmaxf(a0,0.f); xs[1][tid] += fmaxf(a1,0.f);
      xs[2][tid] += fmaxf(a2,0.f); xs[3][tid] += fmaxf(a3,0.f);
    }
    __syncthreads();
  }
  *(float4*)(ft + (size_t)(r0+lr)*H_ + lc) = *(float4*)&xs[lr][lc];
}

// ---------------------------------------------------------------- K5: emission LSE via MFMA
// logits are tiny (|x| < ~1): no max-subtraction needed, accumulate sum(exp) directly.
#define LSE_VSPLIT 16
#define LSE_VPB    2000
#define LSE_CHUNKS 125

__global__ __launch_bounds__(256) void k_lse_mfma(
    const float* __restrict__ ft, const float* __restrict__ emb, float* __restrict__ part)
{
  int tid = threadIdx.x;
  int lane = tid & 63;
  int w = tid >> 6;
  int q = blockIdx.x;
  int jb = blockIdx.y * 64 + w * 16;
  int r16 = lane & 15, kb = lane >> 4;

  short8 A[8];
  {
    const float* arow = ft + (size_t)(jb + r16) * H_ + kb * 8;
#pragma unroll
    for (int ks = 0; ks < 8; ++ks) {
      float4 a = *(const float4*)(arow + ks * 32);
      float4 b = *(const float4*)(arow + ks * 32 + 4);
      A[ks] = pack8(a, b);
    }
  }
  float s0 = 0.f, s1 = 0.f, s2 = 0.f, s3 = 0.f;
  const float* embq = emb + (size_t)q * LSE_VPB * H_;
#pragma unroll 1
  for (int ch = 0; ch < LSE_CHUNKS; ++ch) {
    const float* brow = embq + (size_t)(ch * 16 + r16) * H_ + kb * 8;
    floatx4 acca = {0,0,0,0}, accb = {0,0,0,0};
#pragma unroll
    for (int ks = 0; ks < 8; ks += 2) {
      float4 x0 = *(const float4*)(brow + ks * 32);
      float4 y0 = *(const float4*)(brow + ks * 32 + 4);
      float4 x1 = *(const float4*)(brow + ks * 32 + 32);
      float4 y1 = *(const float4*)(brow + ks * 32 + 36);
      acca = __builtin_amdgcn_mfma_f32_16x16x32_bf16(A[ks],   pack8(x0, y0), acca, 0, 0, 0);
      accb = __builtin_amdgcn_mfma_f32_16x16x32_bf16(A[ks+1], pack8(x1, y1), accb, 0, 0, 0);
    }
    s0 += __expf(acca[0] + accb[0]);
    s1 += __expf(acca[1] + accb[1]);
    s2 += __expf(acca[2] + accb[2]);
    s3 += __expf(acca[3] + accb[3]);
  }
  // reduce over the 16 cols (lanes differing in bits 0..3)
#pragma unroll
  for (int mm = 1; mm <= 8; mm <<= 1) {
    s0 += __shfl_xor(s0, mm, 64);
    s1 += __shfl_xor(s1, mm, 64);
    s2 += __shfl_xor(s2, mm, 64);
    s3 += __shfl_xor(s3, mm, 64);
  }
  if (r16 == 0) {
    int jrow = jb + kb * 4;
    part[(size_t)(jrow + 0) * LSE_VSPLIT + q] = s0;
    part[(size_t)(jrow + 1) * LSE_VSPLIT + q] = s1;
    part[(size_t)(jrow + 2) * LSE_VSPLIT + q] = s2;
    part[(size_t)(jrow + 3) * LSE_VSPLIT + q] = s3;
  }
}

// ---------------------------------------------------------------- K6: combine LSE partials
__global__ __launch_bounds__(256) void k_lse_reduce(
    const float* __restrict__ part, float* __restrict__ lse_row)
{
  int row = blockIdx.x * 256 + threadIdx.x;
  const float4* p = (const float4*)(part + (size_t)row * LSE_VSPLIT);
  float4 a = p[0], b = p[1], c = p[2], d = p[3];
  float s = a.x+a.y+a.z+a.w + b.x+b.y+b.z+b.w + c.x+c.y+c.z+c.w + d.x+d.y+d.z+d.w;
  lse_row[row] = __logf(s);
}

// ---------------------------------------------------------------- K7: EEXP via MFMA (gathered B)
__global__ __launch_bounds__(256) void k_eexp_mfma(
    const float* __restrict__ ft, const float* __restrict__ emb, const int* __restrict__ text,
    const float* __restrict__ lse_row, float* __restrict__ EEXP)
{
  int tid = threadIdx.x;
  int lane = tid & 63;
  int w = tid >> 6;
  int jb = blockIdx.y * 64 + w * 16;
  int tb = blockIdx.x * 64;
  int r16 = lane & 15, kb = lane >> 4;

  short8 A[8];
  {
    const float* arow = ft + (size_t)(jb + r16) * H_ + kb * 8;
#pragma unroll
    for (int ks = 0; ks < 8; ++ks) {
      float4 a = *(const float4*)(arow + ks * 32);
      float4 b = *(const float4*)(arow + ks * 32 + 4);
      A[ks] = pack8(a, b);
    }
  }
  float4 lsej = *(const float4*)(lse_row + jb + kb * 4);

#pragma unroll 1
  for (int tc = 0; tc < 4; ++tc) {
    int idx = tb + tc * 16 + r16;
    int tok = text[idx];
    const float* brow = emb + (size_t)tok * H_ + kb * 8;
    floatx4 acca = {0,0,0,0}, accb = {0,0,0,0};
#pragma unroll
    for (int ks = 0; ks < 8; ks += 2) {
      float4 x0 = *(const float4*)(brow + ks * 32);
      float4 y0 = *(const float4*)(brow + ks * 32 + 4);
      float4 x1 = *(const float4*)(brow + ks * 32 + 32);
      float4 y1 = *(const float4*)(brow + ks * 32 + 36);
      acca = __builtin_amdgcn_mfma_f32_16x16x32_bf16(A[ks],   pack8(x0, y0), acca, 0, 0, 0);
      accb = __builtin_amdgcn_mfma_f32_16x16x32_bf16(A[ks+1], pack8(x1, y1), accb, 0, 0, 0);
    }
    float4 o;
    o.x = __expf(acca[0] + accb[0] - lsej.x);
    o.y = __expf(acca[1] + accb[1] - lsej.y);
    o.z = __expf(acca[2] + accb[2] - lsej.z);
    o.w = __expf(acca[3] + accb[3] - lsej.w);
    *(float4*)(EEXP + (size_t)idx * C_ + jb + kb * 4) = o;
  }
}

// ---------------------------------------------------------------- K8: persistent scan, MFMA matvec, all 8 seqs per WG
// 32 WGs, one per 32-column chunk. Per step:
//   poll alpha_{t-1}[8][1024] (tag-in-word) -> pack bf16 to LDS Al
//   4 waves: wave w owns K quarter [w*256,(w+1)*256), both 16-col tiles
//   C[row=seq][col] = sum_k alpha[seq][k] * P[k][col] via mfma_f32_16x16x32_bf16
//   (A rows 8..15 read duplicated seq data via row&7 -> garbage C rows, ignored)
// LDS: Pl 64KB [j][k] bf16 swz ((j&7)<<4), Al 16KB [s][k] bf16 swz (s<<4),
//      red 4KB [w][tb][r][c], gmw 8 f32
#define SCAN_LDS (65536 + 16384 + 4096 + 32)

__global__ __launch_bounds__(256) void k_scan(
    const float* __restrict__ P, const float* __restrict__ EEXP, const float* __restrict__ startv,
    unsigned* __restrict__ eaG, float* __restrict__ evp)
{
  extern __shared__ char smem[];
  char*  Pl  = smem;                                    // 65536 B
  char*  Al  = smem + 65536;                            // 16384 B
  float* red = (float*)(smem + 65536 + 16384);          // 4096 B
  float* gmw = (float*)(smem + 65536 + 16384 + 4096);   // 8 f32

  int tid  = threadIdx.x;
  int c    = blockIdx.x;       // column chunk 0..31
  int lane = tid & 63;
  int w    = tid >> 6;         // wave 0..3 = K quarter
  int seq  = tid >> 5;         // 0..7
  int jj   = tid & 31;         // col within chunk / k-subchunk index

  // ---- t = 0: alpha_0 for own columns (tag 1), before P staging
  {
    int col = c*CW + jj;
    float val = __expf(startv[col]) * EEXP[((size_t)seq*T_ + 0)*C_ + col];
    unsigned word = ((unsigned)f2bf(val) << 16) | 1u;
    __hip_atomic_store(&eaG[(size_t)(0*N_ + seq)*C_ + col], word,
                       __ATOMIC_RELAXED, __HIP_MEMORY_SCOPE_AGENT);
  }

  // ---- stage P slice -> Pl bf16 [j][k], byte = j*2048 + (2k ^ ((j&7)<<4))
  {
    int j4 = (tid & 7) * 4;
    int irow = tid >> 3;
    for (int rep = 0; rep < 32; ++rep) {
      int i = rep*32 + irow;
      float4 v = *(const float4*)(P + (size_t)i*C_ + c*CW + j4);
      int ib = 2*i;
      *(unsigned short*)(Pl + (size_t)(j4+0)*2048 + (ib ^ (((j4+0)&7)<<4))) = f2bf(v.x);
      *(unsigned short*)(Pl + (size_t)(j4+1)*2048 + (ib ^ (((j4+1)&7)<<4))) = f2bf(v.y);
      *(unsigned short*)(Pl + (size_t)(j4+2)*2048 + (ib ^ (((j4+2)&7)<<4))) = f2bf(v.z);
      *(unsigned short*)(Pl + (size_t)(j4+3)*2048 + (ib ^ (((j4+3)&7)<<4))) = f2bf(v.w);
    }
  }
  __syncthreads();

  float logscale = 0.f;  // meaningful for tid<8 (tid == seq)
  const unsigned long long TMASK = 0x0000ffff0000ffffULL;

#pragma unroll 1
  for (int t = 1; t < T_; ++t) {
    int pprev = (t-1) & 1, pcur = t & 1;

    float eexp_reg = EEXP[((size_t)seq*T_ + t)*C_ + c*CW + jj];

    // ---- poll alpha_{t-1}: thread owns seq (tid>>5), 32 words at k0=(tid&31)*32
    {
      int k0 = jj * 32;
      unsigned long long* src = (unsigned long long*)(eaG + ((size_t)(pprev*N_ + seq)*C_ + k0));
      unsigned long long tpair = (unsigned long long)(unsigned)t | ((unsigned long long)(unsigned)t << 32);
      unsigned long long v[16];
      int guard = 0;
      for (;;) {
#pragma unroll
        for (int u = 0; u < 16; ++u)
          v[u] = __hip_atomic_load(src+u, __ATOMIC_RELAXED, __HIP_MEMORY_SCOPE_AGENT);
        bool ok = true;
#pragma unroll
        for (int u = 0; u < 16; ++u) ok &= ((v[u] & TMASK) == tpair);
        if (ok) break;
        __builtin_amdgcn_s_sleep(1);
        if (++guard > 2000000) break;
      }
      float m = 0.f;  // alpha >= 0
      unsigned pk[16];
#pragma unroll
      for (int u = 0; u < 16; ++u) {
        unsigned wlo = (unsigned)v[u], whi = (unsigned)(v[u] >> 32);
        m = fmaxf(m, fmaxf(__uint_as_float(wlo & 0xffff0000u),
                           __uint_as_float(whi & 0xffff0000u)));
        pk[u] = (wlo >> 16) | (whi & 0xffff0000u);
      }
      char* dst = Al + seq*2048;
      int kb2 = 2*k0;
#pragma unroll
      for (int q = 0; q < 4; ++q)
        *(uint4*)(dst + ((kb2 + q*16) ^ (seq<<4))) = *(const uint4*)&pk[q*4];
      // per-seq max over 32 lanes (lanes 0-31 / 32-63 are distinct seqs in a wave)
#pragma unroll
      for (int mm = 16; mm; mm >>= 1) m = fmaxf(m, __shfl_xor(m, mm, 64));
      if (jj == 0) gmw[seq] = m;
    }
    __syncthreads();

    if (tid < 8) logscale += __logf(gmw[tid]);

    // ---- A fragments: row = lane&7 (seq), 8 consecutive k per lane
    short8 Afrag[8];
    {
      int r = lane & 7;
      int ks = (lane >> 4) * 8;
      char* ap = Al + (size_t)r*2048;
      int rswz = r << 4;
#pragma unroll
      for (int kb = 0; kb < 8; ++kb) {
        int kby = 2*(w*256 + kb*32 + ks);
        Afrag[kb] = *(const short8*)(ap + (kby ^ rswz));
      }
    }
    // ---- MFMA matvec: 2 col tiles x 8 k-blocks
    int j0 = lane & 15;
    const char* bp0 = Pl + (size_t)j0*2048;
    const char* bp1 = Pl + (size_t)(16+j0)*2048;
    int jswz = (j0 & 7) << 4;
    int ks = (lane >> 4) * 8;
    floatx4 acc0 = {0,0,0,0}, acc1 = {0,0,0,0};
#pragma unroll
    for (int kb = 0; kb < 8; ++kb) {
      int kby = 2*(w*256 + kb*32 + ks);
      short8 b0 = *(const short8*)(bp0 + (kby ^ jswz));
      short8 b1 = *(const short8*)(bp1 + (kby ^ jswz));
      acc0 = __builtin_amdgcn_mfma_f32_16x16x32_bf16(Afrag[kb], b0, acc0, 0, 0, 0);
      acc1 = __builtin_amdgcn_mfma_f32_16x16x32_bf16(Afrag[kb], b1, acc1, 0, 0, 0);
    }
    // lanes 0..31 hold valid rows 0..7: row = (lane>>4)*4 + reg
    if (lane < 32) {
      int rbase = (lane >> 4) * 4;
#pragma unroll
      for (int q = 0; q < 4; ++q) {
        red[((w*2+0)*8 + rbase + q)*16 + j0] = acc0[q];
        red[((w*2+1)*8 + rbase + q)*16 + j0] = acc1[q];
      }
    }
    __syncthreads();

    // ---- finalize: thread -> (seq, col jj)
    {
      int tb = jj >> 4, jc = jj & 15;
      float sum = red[((0*2+tb)*8 + seq)*16 + jc] + red[((1*2+tb)*8 + seq)*16 + jc]
                + red[((2*2+tb)*8 + seq)*16 + jc] + red[((3*2+tb)*8 + seq)*16 + jc];
      float val = (sum / gmw[seq]) * eexp_reg;
      unsigned word = ((unsigned)f2bf(val) << 16) | (unsigned)(t+1);
      __hip_atomic_store(&eaG[(size_t)(pcur*N_ + seq)*C_ + c*CW + jj], word,
                         __ATOMIC_RELAXED, __HIP_MEMORY_SCOPE_AGENT);
    }
  }

  // ---- tail: WG 0 gathers alpha_{T-1}, per-seq logsumexp
  if (c == 0) {
    int k0 = jj * 32;
    unsigned long long* src = (unsigned long long*)(eaG + ((size_t)(1*N_ + seq)*C_ + k0));
    unsigned long long tpair = (unsigned long long)(unsigned)T_ | ((unsigned long long)(unsigned)T_ << 32);
    unsigned long long v[16];
    int guard = 0;
    for (;;) {
#pragma unroll
      for (int u = 0; u < 16; ++u)
        v[u] = __hip_atomic_load(src+u, __ATOMIC_RELAXED, __HIP_MEMORY_SCOPE_AGENT);
      bool ok = true;
#pragma unroll
      for (int u = 0; u < 16; ++u) ok &= ((v[u] & TMASK) == tpair);
      if (ok) break;
      __builtin_amdgcn_s_sleep(1);
      if (++guard > 2000000) break;
    }
    float s8 = 0.f;
#pragma unroll
    for (int u = 0; u < 16; ++u) {
      s8 += __uint_as_float((unsigned)v[u]        & 0xffff0000u);
      s8 += __uint_as_float((unsigned)(v[u]>>32)  & 0xffff0000u);
    }
#pragma unroll
    for (int mm = 16; mm; mm >>= 1) s8 += __shfl_xor(s8, mm, 64);
    if (jj == 0) gmw[seq] = s8;
    __syncthreads();
    if (tid < 8) evp[tid] = logscale + __logf(gmw[tid]);
  }
}

// ---------------------------------------------------------------- K9: final sum
__global__ void k_final(const float* __restrict__ evp, float* __restrict__ out)
{
  if (threadIdx.x == 0) {
    float s = 0.f;
#pragma unroll
    for (int i = 0; i < N_; ++i) s += evp[i];
    out[0] = s;
  }
}

// ----------------------------------------------------------------
extern "C" void kernel_launch(void* const* d_in, const int* in_sizes, int n_in,
                              void* d_out, int out_size, void* d_ws, size_t ws_size,
                              hipStream_t stream)
{
  const int*   text      = (const int*)  d_in[0];
  const float* start_emb = (const float*)d_in[1];
  const float* slw       = (const float*)d_in[2];
  const float* slb       = (const float*)d_in[3];
  const float* sW1       = (const float*)d_in[4];
  const float* sb1       = (const float*)d_in[5];
  const float* sW2       = (const float*)d_in[6];
  const float* sb2       = (const float*)d_in[7];
  const float* state_emb = (const float*)d_in[8];
  const float* nse       = (const float*)d_in[9];
  const float* pre_emb   = (const float*)d_in[10];
  const float* tW1       = (const float*)d_in[11];
  const float* tb1       = (const float*)d_in[12];
  const float* tW2       = (const float*)d_in[13];
  const float* tb2       = (const float*)d_in[14];
  const float* term_emb  = (const float*)d_in[15];

  char* ws = (char*)d_ws;
  float*    w_start = (float*)   (ws + OFF_START);
  float*    w_lse   = (float*)   (ws + OFF_LSE);
  float*    w_evp   = (float*)   (ws + OFF_EVP);
  unsigned* w_ea    = (unsigned*)(ws + OFF_EA);
  float*    w_ft    = (float*)   (ws + OFF_FT);
  float*    w_P     = (float*)   (ws + OFF_P);
  float*    w_part  = (float*)   (ws + OFF_PART);
  float*    w_eexp  = (float*)   (ws + OFF_EEXP);

  (void)hipMemsetAsync(w_ea, 0, 2*N_*C_*sizeof(unsigned), stream);

  k_start<<<1, 256, 0, stream>>>(start_emb, slw, slb, sW1, sb1, sW2, sb2, nse, w_start);
  k_gemm_cc<<<dim3(16,16), 256, 0, stream>>>(state_emb, nse, w_P);
  k_softmax_rows<<<C_, 256, 0, stream>>>(w_P);
  k_mlp<<<C_/4, 256, 0, stream>>>(pre_emb, tW1, tb1, tW2, tb2, w_ft);
  k_lse_mfma<<<dim3(LSE_VSPLIT, 16), 256, 0, stream>>>(w_ft, term_emb, w_part);
  k_lse_reduce<<<4, 256, 0, stream>>>(w_part, w_lse);
  k_eexp_mfma<<<dim3(64, 16), 256, 0, stream>>>(w_ft, term_emb, text, w_lse, w_eexp);

  (void)hipFuncSetAttribute((const void*)k_scan, hipFuncAttributeMaxDynamicSharedMemorySize, SCAN_LDS);
  k_scan<<<32, 256, SCAN_LDS, stream>>>(w_P, w_eexp, w_start, w_ea, w_evp);
  k_final<<<1, 64, 0, stream>>>(w_evp, (float*)d_out);
}

// Round 2
// 1759.313 us; speedup vs baseline: 1.4516x; 1.4516x over previous
//
#include <hip/hip_runtime.h>
#include <stdint.h>
#include <stddef.h>

#define N_ 8
#define T_ 512
#define C_ 1024
#define H_ 256
#define V_ 32000
#define CW 32      // columns per chunk

// workspace byte offsets
#define OFF_START   0u
#define OFF_LSE     4096u
#define OFF_EVP     8192u        // 8 f32 per-seq evidence
#define OFF_EA      16384u       // 2*8*1024 tagged u32 = 64KB (memset 0 each launch)
#define OFF_FT      81920u       // 1024*256 f32 = 1MB
#define OFF_P       1130496u     // 1024*1024 f32 = 4MB
#define OFF_PART    5324800u     // 1024*16 f32 partials
#define OFF_EEXP    5849088u     // 4096*1024 f32 = 16MB

typedef __attribute__((ext_vector_type(8))) short short8;
typedef __attribute__((ext_vector_type(4))) float floatx4;

__device__ __forceinline__ float dot4(float4 a, float4 b) {
  return a.x*b.x + a.y*b.y + a.z*b.z + a.w*b.w;
}

__device__ __forceinline__ unsigned short f2bf(float f) {
  unsigned u = __float_as_uint(f);
  unsigned r = u + 0x7fffu + ((u >> 16) & 1u);   // round-to-nearest-even
  return (unsigned short)(r >> 16);
}

__device__ __forceinline__ unsigned pk_bf2(float x, float y) {
  return ((unsigned)f2bf(y) << 16) | (unsigned)f2bf(x);
}

__device__ __forceinline__ short8 pack8(float4 a, float4 b) {
  union { short8 s; unsigned u[4]; } r;
  r.u[0] = pk_bf2(a.x, a.y);
  r.u[1] = pk_bf2(a.z, a.w);
  r.u[2] = pk_bf2(b.x, b.y);
  r.u[3] = pk_bf2(b.z, b.w);
  return r.s;
}

// ---------------------------------------------------------------- K1: start distribution
__global__ __launch_bounds__(256) void k_start(
    const float* __restrict__ se, const float* __restrict__ lw, const float* __restrict__ lb,
    const float* __restrict__ W1, const float* __restrict__ b1,
    const float* __restrict__ W2, const float* __restrict__ b2,
    const float* __restrict__ nse, float* __restrict__ out_start)
{
  __shared__ float xs[H_], fx[H_], h1[H_];
  __shared__ float lg[C_];
  __shared__ float redk[4];
  int tid = threadIdx.x;
  xs[tid] = se[tid];
  __syncthreads();
  {
    float acc = lb[tid];
    const float4* wr = (const float4*)(lw + (size_t)tid*H_);
    for (int k = 0; k < H_/4; ++k) acc += dot4(wr[k], *(const float4*)&xs[k*4]);
    fx[tid] = acc;
  }
  __syncthreads();
  for (int L = 0; L < 2; ++L) {
    {
      float acc = b1[L*H_ + tid];
      const float4* wr = (const float4*)(W1 + (size_t)(L*H_ + tid)*H_);
      for (int k = 0; k < H_/4; ++k) acc += dot4(wr[k], *(const float4*)&fx[k*4]);
      h1[tid] = fmaxf(acc, 0.f);
    }
    __syncthreads();
    {
      float acc = b2[L*H_ + tid];
      const float4* wr = (const float4*)(W2 + (size_t)(L*H_ + tid)*H_);
      for (int k = 0; k < H_/4; ++k) acc += dot4(wr[k], *(const float4*)&h1[k*4]);
      fx[tid] += fmaxf(acc, 0.f);
    }
    __syncthreads();
  }
  float lmax = -1e30f;
  for (int r = 0; r < 4; ++r) {
    int cc = tid + r*256;
    float acc = 0.f;
    const float4* er = (const float4*)(nse + (size_t)cc*H_);
    for (int k = 0; k < H_/4; ++k) acc += dot4(er[k], *(const float4*)&fx[k*4]);
    lg[cc] = acc;
    lmax = fmaxf(lmax, acc);
  }
  for (int m = 32; m; m >>= 1) lmax = fmaxf(lmax, __shfl_xor(lmax, m, 64));
  if ((tid & 63) == 0) redk[tid >> 6] = lmax;
  __syncthreads();
  float M = fmaxf(fmaxf(redk[0], redk[1]), fmaxf(redk[2], redk[3]));
  __syncthreads();
  float ssum = 0.f;
  for (int r = 0; r < 4; ++r) ssum += __expf(lg[tid + r*256] - M);
  for (int m = 32; m; m >>= 1) ssum += __shfl_xor(ssum, m, 64);
  if ((tid & 63) == 0) redk[tid >> 6] = ssum;
  __syncthreads();
  float S = redk[0] + redk[1] + redk[2] + redk[3];
  float lse = M + __logf(S);
  for (int r = 0; r < 4; ++r) {
    int cc = tid + r*256;
    out_start[cc] = lg[cc] - lse;
  }
}

// ---------------------------------------------------------------- K2: transition logits GEMM (f32)
__global__ __launch_bounds__(256) void k_gemm_cc(
    const float* __restrict__ A, const float* __restrict__ B, float* __restrict__ Cout)
{
  __shared__ float As[64][69];
  __shared__ float Bs[64][69];
  int tid = threadIdx.x;
  int bi = blockIdx.y, bj = blockIdx.x;
  int sr = tid >> 2, sq = tid & 3;
  int tx = tid & 15, ty = tid >> 4;
  float acc[4][4] = {};
  for (int kb = 0; kb < H_; kb += 64) {
    __syncthreads();
    {
      const float* ar = A + (size_t)(bi*64 + sr)*H_ + kb + sq*16;
      const float* br = B + (size_t)(bj*64 + sr)*H_ + kb + sq*16;
#pragma unroll
      for (int qq = 0; qq < 4; ++qq) {
        float4 av = *(const float4*)(ar + qq*4);
        float4 bv = *(const float4*)(br + qq*4);
        int kk = sq*16 + qq*4;
        As[sr][kk+0]=av.x; As[sr][kk+1]=av.y; As[sr][kk+2]=av.z; As[sr][kk+3]=av.w;
        Bs[sr][kk+0]=bv.x; Bs[sr][kk+1]=bv.y; Bs[sr][kk+2]=bv.z; Bs[sr][kk+3]=bv.w;
      }
    }
    __syncthreads();
#pragma unroll 4
    for (int k = 0; k < 64; ++k) {
      float a0 = As[ty*4+0][k], a1 = As[ty*4+1][k], a2 = As[ty*4+2][k], a3 = As[ty*4+3][k];
      float b0 = Bs[tx*4+0][k], b1 = Bs[tx*4+1][k], b2 = Bs[tx*4+2][k], b3 = Bs[tx*4+3][k];
      acc[0][0]+=a0*b0; acc[0][1]+=a0*b1; acc[0][2]+=a0*b2; acc[0][3]+=a0*b3;
      acc[1][0]+=a1*b0; acc[1][1]+=a1*b1; acc[1][2]+=a1*b2; acc[1][3]+=a1*b3;
      acc[2][0]+=a2*b0; acc[2][1]+=a2*b1; acc[2][2]+=a2*b2; acc[2][3]+=a2*b3;
      acc[3][0]+=a3*b0; acc[3][1]+=a3*b1; acc[3][2]+=a3*b2; acc[3][3]+=a3*b3;
    }
  }
#pragma unroll
  for (int ii = 0; ii < 4; ++ii)
#pragma unroll
    for (int jj = 0; jj < 4; ++jj)
      Cout[(size_t)(bi*64 + ty*4 + ii)*C_ + bj*64 + tx*4 + jj] = acc[ii][jj];
}

// ---------------------------------------------------------------- K3: row softmax in place
__global__ __launch_bounds__(256) void k_softmax_rows(float* __restrict__ P)
{
  __shared__ float redk[4];
  int row = blockIdx.x, tid = threadIdx.x;
  float4* pr = (float4*)(P + (size_t)row*C_);
  float4 v = pr[tid];
  float m = fmaxf(fmaxf(v.x, v.y), fmaxf(v.z, v.w));
  for (int mm = 32; mm; mm >>= 1) m = fmaxf(m, __shfl_xor(m, mm, 64));
  if ((tid & 63) == 0) redk[tid >> 6] = m;
  __syncthreads();
  float M = fmaxf(fmaxf(redk[0], redk[1]), fmaxf(redk[2], redk[3]));
  __syncthreads();
  float4 e;
  e.x = __expf(v.x - M); e.y = __expf(v.y - M); e.z = __expf(v.z - M); e.w = __expf(v.w - M);
  float s = e.x + e.y + e.z + e.w;
  for (int mm = 32; mm; mm >>= 1) s += __shfl_xor(s, mm, 64);
  if ((tid & 63) == 0) redk[tid >> 6] = s;
  __syncthreads();
  float S = redk[0] + redk[1] + redk[2] + redk[3];
  float inv = 1.0f / S;
  e.x *= inv; e.y *= inv; e.z *= inv; e.w *= inv;
  pr[tid] = e;
}

// ---------------------------------------------------------------- K4: terminal MLP
__global__ __launch_bounds__(256) void k_mlp(
    const float* __restrict__ inp, const float* __restrict__ W1, const float* __restrict__ b1,
    const float* __restrict__ W2, const float* __restrict__ b2, float* __restrict__ ft)
{
  __shared__ float xs[4][H_];
  __shared__ float hs[4][H_];
  int tid = threadIdx.x;
  int r0 = blockIdx.x * 4;
  int lr = tid >> 6, lc = (tid & 63) * 4;
  *(float4*)&xs[lr][lc] = *(const float4*)(inp + (size_t)(r0+lr)*H_ + lc);
  __syncthreads();
  for (int L = 0; L < 2; ++L) {
    {
      const float4* wr = (const float4*)(W1 + (size_t)(L*H_ + tid)*H_);
      float bb = b1[L*H_ + tid];
      float a0=bb, a1=bb, a2=bb, a3=bb;
      for (int k = 0; k < H_/4; ++k) {
        float4 w = wr[k];
        a0 += dot4(w, *(const float4*)&xs[0][k*4]);
        a1 += dot4(w, *(const float4*)&xs[1][k*4]);
        a2 += dot4(w, *(const float4*)&xs[2][k*4]);
        a3 += dot4(w, *(const float4*)&xs[3][k*4]);
      }
      hs[0][tid]=fmaxf(a0,0.f); hs[1][tid]=fmaxf(a1,0.f);
      hs[2][tid]=fmaxf(a2,0.f); hs[3][tid]=fmaxf(a3,0.f);
    }
    __syncthreads();
    {
      const float4* wr = (const float4*)(W2 + (size_t)(L*H_ + tid)*H_);
      float bb = b2[L*H_ + tid];
      float a0=bb, a1=bb, a2=bb, a3=bb;
      for (int k = 0; k < H_/4; ++k) {
        float4 w = wr[k];
        a0 += dot4(w, *(const float4*)&hs[0][k*4]);
        a1 += dot4(w, *(const float4*)&hs[1][k*4]);
        a2 += dot4(w, *(const float4*)&hs[2][k*4]);
        a3 += dot4(w, *(const float4*)&hs[3][k*4]);
      }
      xs[0][tid] += fmaxf(a0,0.f); xs[1][tid] += fmaxf(a1,0.f);
      xs[2][tid] += fmaxf(a2,0.f); xs[3][tid] += fmaxf(a3,0.f);
    }
    __syncthreads();
  }
  *(float4*)(ft + (size_t)(r0+lr)*H_ + lc) = *(float4*)&xs[lr][lc];
}

// ---------------------------------------------------------------- K5: emission LSE via MFMA
// logits are tiny (|x| < ~1): no max-subtraction needed, accumulate sum(exp) directly.
#define LSE_VSPLIT 16
#define LSE_VPB    2000
#define LSE_CHUNKS 125

__global__ __launch_bounds__(256) void k_lse_mfma(
    const float* __restrict__ ft, const float* __restrict__ emb, float* __restrict__ part)
{
  int tid = threadIdx.x;
  int lane = tid & 63;
  int w = tid >> 6;
  int q = blockIdx.x;
  int jb = blockIdx.y * 64 + w * 16;
  int r16 = lane & 15, kb = lane >> 4;

  short8 A[8];
  {
    const float* arow = ft + (size_t)(jb + r16) * H_ + kb * 8;
#pragma unroll
    for (int ks = 0; ks < 8; ++ks) {
      float4 a = *(const float4*)(arow + ks * 32);
      float4 b = *(const float4*)(arow + ks * 32 + 4);
      A[ks] = pack8(a, b);
    }
  }
  float s0 = 0.f, s1 = 0.f, s2 = 0.f, s3 = 0.f;
  const float* embq = emb + (size_t)q * LSE_VPB * H_;
#pragma unroll 1
  for (int ch = 0; ch < LSE_CHUNKS; ++ch) {
    const float* brow = embq + (size_t)(ch * 16 + r16) * H_ + kb * 8;
    floatx4 acca = {0,0,0,0}, accb = {0,0,0,0};
#pragma unroll
    for (int ks = 0; ks < 8; ks += 2) {
      float4 x0 = *(const float4*)(brow + ks * 32);
      float4 y0 = *(const float4*)(brow + ks * 32 + 4);
      float4 x1 = *(const float4*)(brow + ks * 32 + 32);
      float4 y1 = *(const float4*)(brow + ks * 32 + 36);
      acca = __builtin_amdgcn_mfma_f32_16x16x32_bf16(A[ks],   pack8(x0, y0), acca, 0, 0, 0);
      accb = __builtin_amdgcn_mfma_f32_16x16x32_bf16(A[ks+1], pack8(x1, y1), accb, 0, 0, 0);
    }
    s0 += __expf(acca[0] + accb[0]);
    s1 += __expf(acca[1] + accb[1]);
    s2 += __expf(acca[2] + accb[2]);
    s3 += __expf(acca[3] + accb[3]);
  }
  // reduce over the 16 cols (lanes differing in bits 0..3)
#pragma unroll
  for (int mm = 1; mm <= 8; mm <<= 1) {
    s0 += __shfl_xor(s0, mm, 64);
    s1 += __shfl_xor(s1, mm, 64);
    s2 += __shfl_xor(s2, mm, 64);
    s3 += __shfl_xor(s3, mm, 64);
  }
  if (r16 == 0) {
    int jrow = jb + kb * 4;
    part[(size_t)(jrow + 0) * LSE_VSPLIT + q] = s0;
    part[(size_t)(jrow + 1) * LSE_VSPLIT + q] = s1;
    part[(size_t)(jrow + 2) * LSE_VSPLIT + q] = s2;
    part[(size_t)(jrow + 3) * LSE_VSPLIT + q] = s3;
  }
}

// ---------------------------------------------------------------- K6: combine LSE partials
__global__ __launch_bounds__(256) void k_lse_reduce(
    const float* __restrict__ part, float* __restrict__ lse_row)
{
  int row = blockIdx.x * 256 + threadIdx.x;
  const float4* p = (const float4*)(part + (size_t)row * LSE_VSPLIT);
  float4 a = p[0], b = p[1], c = p[2], d = p[3];
  float s = a.x+a.y+a.z+a.w + b.x+b.y+b.z+b.w + c.x+c.y+c.z+c.w + d.x+d.y+d.z+d.w;
  lse_row[row] = __logf(s);
}

// ---------------------------------------------------------------- K7: EEXP via MFMA (gathered B)
__global__ __launch_bounds__(256) void k_eexp_mfma(
    const float* __restrict__ ft, const float* __restrict__ emb, const int* __restrict__ text,
    const float* __restrict__ lse_row, float* __restrict__ EEXP)
{
  int tid = threadIdx.x;
  int lane = tid & 63;
  int w = tid >> 6;
  int jb = blockIdx.y * 64 + w * 16;
  int tb = blockIdx.x * 64;
  int r16 = lane & 15, kb = lane >> 4;

  short8 A[8];
  {
    const float* arow = ft + (size_t)(jb + r16) * H_ + kb * 8;
#pragma unroll
    for (int ks = 0; ks < 8; ++ks) {
      float4 a = *(const float4*)(arow + ks * 32);
      float4 b = *(const float4*)(arow + ks * 32 + 4);
      A[ks] = pack8(a, b);
    }
  }
  float4 lsej = *(const float4*)(lse_row + jb + kb * 4);

#pragma unroll 1
  for (int tc = 0; tc < 4; ++tc) {
    int idx = tb + tc * 16 + r16;
    int tok = text[idx];
    const float* brow = emb + (size_t)tok * H_ + kb * 8;
    floatx4 acca = {0,0,0,0}, accb = {0,0,0,0};
#pragma unroll
    for (int ks = 0; ks < 8; ks += 2) {
      float4 x0 = *(const float4*)(brow + ks * 32);
      float4 y0 = *(const float4*)(brow + ks * 32 + 4);
      float4 x1 = *(const float4*)(brow + ks * 32 + 32);
      float4 y1 = *(const float4*)(brow + ks * 32 + 36);
      acca = __builtin_amdgcn_mfma_f32_16x16x32_bf16(A[ks],   pack8(x0, y0), acca, 0, 0, 0);
      accb = __builtin_amdgcn_mfma_f32_16x16x32_bf16(A[ks+1], pack8(x1, y1), accb, 0, 0, 0);
    }
    float4 o;
    o.x = __expf(acca[0] + accb[0] - lsej.x);
    o.y = __expf(acca[1] + accb[1] - lsej.y);
    o.z = __expf(acca[2] + accb[2] - lsej.z);
    o.w = __expf(acca[3] + accb[3] - lsej.w);
    *(float4*)(EEXP + (size_t)idx * C_ + jb + kb * 4) = o;
  }
}

// ---------------------------------------------------------------- K8: persistent scan
// 4 groups x 32 WGs (old proven comm topology: c = bid>>2, ng = bid&3).
// Each WG: 2 seqs, 32 output cols. MFMA matvec with OUT-OF-ORDER per-block ingest:
// wave w owns K-quarter [w*256,(w+1)*256) = 8 producer blocks of 32 cols.
// Per block: 1 u32 atomic load/lane + ballot; on completion bounce through private
// LDS slot -> A-fragment -> 2 MFMA accumulations. Arrived blocks are processed
// while polling stragglers. ONE barrier/step (red/gmx double-buffered by parity).
// LDS: Pl 64KB [col32][k1024] bf16 swz((col&7)<<4); Bl 4KB [w][b][seq2][kk32] u16;
//      red 2KB [p][w][tile][row2][16] f32; gmx 64B [p][w][s]; gmw 16B tail.
#define SCAN_LDS 71808

__global__ __launch_bounds__(256) void k_scan(
    const float* __restrict__ P, const float* __restrict__ EEXP, const float* __restrict__ startv,
    unsigned* __restrict__ eaG, float* __restrict__ evp)
{
  extern __shared__ char smem[];
  char*  Pl  = smem;                       // 65536 B
  char*  Bl  = smem + 65536;               // 4096 B
  float* red = (float*)(smem + 69632);     // 2048 B
  float* gmx = (float*)(smem + 71680);     // 64 B
  float* gmw = (float*)(smem + 71744);     // 16 B

  int tid  = threadIdx.x;
  int bid  = blockIdx.x;
  int c    = bid >> 2;          // chunk 0..31
  int ng   = bid & 3;           // group 0..3
  int n0   = ng * 2;
  int lane = tid & 63;
  int w    = tid >> 6;          // wave 0..3 = K quarter
  int seqh = lane >> 5;         // 0/1 within group
  int kk   = lane & 31;

  // ---- t = 0: alpha_0 for own columns (tag 1), before P staging
  if (tid < 64) {
    int s = tid >> 5, j = tid & 31;
    int col = c*CW + j;
    float val = __expf(startv[col]) * EEXP[((size_t)(n0+s)*T_ + 0)*C_ + col];
    unsigned word = ((unsigned)f2bf(val) << 16) | 1u;
    __hip_atomic_store(&eaG[(size_t)(0*N_ + n0+s)*C_ + col], word,
                       __ATOMIC_RELAXED, __HIP_MEMORY_SCOPE_AGENT);
  }

  // ---- stage P slice -> Pl bf16 [col][k], byte = col*2048 + (2k ^ ((col&7)<<4))
  {
    int j4 = (tid & 7) * 4;
    int irow = tid >> 3;
    for (int rep = 0; rep < 32; ++rep) {
      int i = rep*32 + irow;
      float4 v = *(const float4*)(P + (size_t)i*C_ + c*CW + j4);
      int ib = 2*i;
      *(unsigned short*)(Pl + (size_t)(j4+0)*2048 + (ib ^ (((j4+0)&7)<<4))) = f2bf(v.x);
      *(unsigned short*)(Pl + (size_t)(j4+1)*2048 + (ib ^ (((j4+1)&7)<<4))) = f2bf(v.y);
      *(unsigned short*)(Pl + (size_t)(j4+2)*2048 + (ib ^ (((j4+2)&7)<<4))) = f2bf(v.z);
      *(unsigned short*)(Pl + (size_t)(j4+3)*2048 + (ib ^ (((j4+3)&7)<<4))) = f2bf(v.w);
    }
  }
  __syncthreads();

  float ls0 = 0.f, ls1 = 0.f;

  // wave-constant addressing
  int fidx = w*16 + (lane & 15);          // finalize slot (valid when lane<16)
  int fs   = fidx >> 5, fcol = fidx & 31;
  int j0 = lane & 15;
  const char* bp0 = Pl + (size_t)j0*2048;
  const char* bp1 = Pl + (size_t)(16+j0)*2048;
  int jswz = (j0 & 7) << 4;
  int ksub = lane >> 4;                   // 0..3
  char* blw = Bl + w*1024;
  int arow = (lane & 15) & 1;

#pragma unroll 1
  for (int t = 1; t < T_; ++t) {
    int pprev = (t-1) & 1, pcur = t & 1;

    float eexp_reg = 0.f;
    if ((lane & 48) == 0 || lane < 16)    // lanes 0..15 only (cheap uniform-ish guard)
      eexp_reg = EEXP[((size_t)(n0+fs)*T_ + t)*C_ + c*CW + fcol];

    // ---- poll + out-of-order ingest
    unsigned pend = 0xffu;
    float m = 0.f;
    floatx4 acc0 = {0,0,0,0}, acc1 = {0,0,0,0};
    unsigned tgt = (unsigned)t;
    unsigned* pbase = eaG + ((size_t)(pprev*N_ + n0+seqh)*C_ + w*256 + kk);
    int guard = 0;
    while (pend) {
      unsigned v[8];
      unsigned got = 0;
#pragma unroll
      for (int b = 0; b < 8; ++b) if (pend & (1u<<b))
        v[b] = __hip_atomic_load(pbase + b*32, __ATOMIC_RELAXED, __HIP_MEMORY_SCOPE_AGENT);
#pragma unroll
      for (int b = 0; b < 8; ++b) if (pend & (1u<<b)) {
        if (__ballot((v[b] & 0xffffu) == tgt) == ~0ull) got |= (1u<<b);
      }
      if (got) {
        // write phase: bounce arrived blocks to private LDS slots
#pragma unroll
        for (int b = 0; b < 8; ++b) if (got & (1u<<b)) {
          m = fmaxf(m, __uint_as_float(v[b] & 0xffff0000u));
          *(unsigned short*)(blw + b*128 + seqh*64 + kk*2) = (unsigned short)(v[b] >> 16);
        }
        asm volatile("s_waitcnt lgkmcnt(0)" ::: "memory");
        __builtin_amdgcn_sched_barrier(0);
        // read + MFMA phase
#pragma unroll
        for (int b = 0; b < 8; ++b) if (got & (1u<<b)) {
          short8 af = *(const short8*)(blw + b*128 + arow*64 + ksub*16);
          int kby = 2*(w*256 + b*32 + ksub*8);
          short8 b0 = *(const short8*)(bp0 + (kby ^ jswz));
          short8 b1 = *(const short8*)(bp1 + (kby ^ jswz));
          acc0 = __builtin_amdgcn_mfma_f32_16x16x32_bf16(af, b0, acc0, 0, 0, 0);
          acc1 = __builtin_amdgcn_mfma_f32_16x16x32_bf16(af, b1, acc1, 0, 0, 0);
        }
        pend &= ~got;
      } else {
        __builtin_amdgcn_s_sleep(1);
        if (++guard > 1000000) break;
      }
    }

    // ---- per-seq max within wave (lanes 0-31 = seq0, 32-63 = seq1)
#pragma unroll
    for (int mm = 1; mm <= 16; mm <<= 1) m = fmaxf(m, __shfl_xor(m, mm, 64));
    if (kk == 0) gmx[(pprev*4 + w)*2 + seqh] = m;

    // ---- partials: lanes 0-15 hold C rows 0(seq0),1(seq1) in regs 0,1
    if (lane < 16) {
      int rb = ((pprev*4 + w)*2)*2*16;    // [p][w][tile][row][16]
      red[rb +  0 + j0] = acc0[0];
      red[rb + 16 + j0] = acc0[1];
      red[rb + 32 + j0] = acc1[0];
      red[rb + 48 + j0] = acc1[1];
    }
    __syncthreads();

    // ---- global M + logscale (all threads, broadcast reads)
    float M0 = fmaxf(fmaxf(gmx[(pprev*4+0)*2+0], gmx[(pprev*4+1)*2+0]),
                     fmaxf(gmx[(pprev*4+2)*2+0], gmx[(pprev*4+3)*2+0]));
    float M1 = fmaxf(fmaxf(gmx[(pprev*4+0)*2+1], gmx[(pprev*4+1)*2+1]),
                     fmaxf(gmx[(pprev*4+2)*2+1], gmx[(pprev*4+3)*2+1]));
    ls0 += __logf(M0);
    ls1 += __logf(M1);

    // ---- finalize: 16 lanes/wave, slot fidx -> (fs, fcol)
    if (lane < 16) {
      int tile = fcol >> 4, c16 = fcol & 15;
      float sum = 0.f;
#pragma unroll
      for (int ww = 0; ww < 4; ++ww)
        sum += red[(((pprev*4+ww)*2 + tile)*2 + fs)*16 + c16];
      float val = (sum / (fs ? M1 : M0)) * eexp_reg;
      unsigned word = ((unsigned)f2bf(val) << 16) | (unsigned)(t+1);
      __hip_atomic_store(&eaG[(size_t)(pcur*N_ + n0+fs)*C_ + c*CW + fcol], word,
                         __ATOMIC_RELAXED, __HIP_MEMORY_SCOPE_AGENT);
    }
  }

  // ---- tail: chunk-0 WGs gather alpha_{T-1}, per-seq logsumexp
  if (c == 0) {
    const unsigned long long TMASK = 0x0000ffff0000ffffULL;
    {
      int sq = tid >> 7;
      int ib = (tid & 127) * 8;
      unsigned long long* src = (unsigned long long*)(eaG + ((size_t)(1*N_ + n0+sq)*C_ + ib));
      unsigned long long tpair = (unsigned long long)(unsigned)T_ | ((unsigned long long)(unsigned)T_ << 32);
      unsigned long long v0, v1, v2, v3;
      int guard = 0;
      for (;;) {
        v0 = __hip_atomic_load(src+0, __ATOMIC_RELAXED, __HIP_MEMORY_SCOPE_AGENT);
        v1 = __hip_atomic_load(src+1, __ATOMIC_RELAXED, __HIP_MEMORY_SCOPE_AGENT);
        v2 = __hip_atomic_load(src+2, __ATOMIC_RELAXED, __HIP_MEMORY_SCOPE_AGENT);
        v3 = __hip_atomic_load(src+3, __ATOMIC_RELAXED, __HIP_MEMORY_SCOPE_AGENT);
        bool ok = ((v0 & TMASK) == tpair) & ((v1 & TMASK) == tpair)
                & ((v2 & TMASK) == tpair) & ((v3 & TMASK) == tpair);
        if (ok) break;
        __builtin_amdgcn_s_sleep(1);
        if (++guard > 1000000) break;
      }
      float s8 = __uint_as_float((unsigned)v0       & 0xffff0000u)
               + __uint_as_float((unsigned)(v0>>32) & 0xffff0000u)
               + __uint_as_float((unsigned)v1       & 0xffff0000u)
               + __uint_as_float((unsigned)(v1>>32) & 0xffff0000u)
               + __uint_as_float((unsigned)v2       & 0xffff0000u)
               + __uint_as_float((unsigned)(v2>>32) & 0xffff0000u)
               + __uint_as_float((unsigned)v3       & 0xffff0000u)
               + __uint_as_float((unsigned)(v3>>32) & 0xffff0000u);
#pragma unroll
      for (int mm = 32; mm; mm >>= 1) s8 += __shfl_xor(s8, mm, 64);
      if ((tid & 63) == 0) gmw[tid >> 6] = s8;
    }
    __syncthreads();
    if (tid == 0) {
      float S0 = gmw[0] + gmw[1];
      float S1 = gmw[2] + gmw[3];
      evp[n0]     = ls0 + __logf(S0);
      evp[n0 + 1] = ls1 + __logf(S1);
    }
  }
}

// ---------------------------------------------------------------- K9: final sum
__global__ void k_final(const float* __restrict__ evp, float* __restrict__ out)
{
  if (threadIdx.x == 0) {
    float s = 0.f;
#pragma unroll
    for (int i = 0; i < N_; ++i) s += evp[i];
    out[0] = s;
  }
}

// ----------------------------------------------------------------
extern "C" void kernel_launch(void* const* d_in, const int* in_sizes, int n_in,
                              void* d_out, int out_size, void* d_ws, size_t ws_size,
                              hipStream_t stream)
{
  const int*   text      = (const int*)  d_in[0];
  const float* start_emb = (const float*)d_in[1];
  const float* slw       = (const float*)d_in[2];
  const float* slb       = (const float*)d_in[3];
  const float* sW1       = (const float*)d_in[4];
  const float* sb1       = (const float*)d_in[5];
  const float* sW2       = (const float*)d_in[6];
  const float* sb2       = (const float*)d_in[7];
  const float* state_emb = (const float*)d_in[8];
  const float* nse       = (const float*)d_in[9];
  const float* pre_emb   = (const float*)d_in[10];
  const float* tW1       = (const float*)d_in[11];
  const float* tb1       = (const float*)d_in[12];
  const float* tW2       = (const float*)d_in[13];
  const float* tb2       = (const float*)d_in[14];
  const float* term_emb  = (const float*)d_in[15];

  char* ws = (char*)d_ws;
  float*    w_start = (float*)   (ws + OFF_START);
  float*    w_lse   = (float*)   (ws + OFF_LSE);
  float*    w_evp   = (float*)   (ws + OFF_EVP);
  unsigned* w_ea    = (unsigned*)(ws + OFF_EA);
  float*    w_ft    = (float*)   (ws + OFF_FT);
  float*    w_P     = (float*)   (ws + OFF_P);
  float*    w_part  = (float*)   (ws + OFF_PART);
  float*    w_eexp  = (float*)   (ws + OFF_EEXP);

  (void)hipMemsetAsync(w_ea, 0, 2*N_*C_*sizeof(unsigned), stream);

  k_start<<<1, 256, 0, stream>>>(start_emb, slw, slb, sW1, sb1, sW2, sb2, nse, w_start);
  k_gemm_cc<<<dim3(16,16), 256, 0, stream>>>(state_emb, nse, w_P);
  k_softmax_rows<<<C_, 256, 0, stream>>>(w_P);
  k_mlp<<<C_/4, 256, 0, stream>>>(pre_emb, tW1, tb1, tW2, tb2, w_ft);
  k_lse_mfma<<<dim3(LSE_VSPLIT, 16), 256, 0, stream>>>(w_ft, term_emb, w_part);
  k_lse_reduce<<<4, 256, 0, stream>>>(w_part, w_lse);
  k_eexp_mfma<<<dim3(64, 16), 256, 0, stream>>>(w_ft, term_emb, text, w_lse, w_eexp);

  (void)hipFuncSetAttribute((const void*)k_scan, hipFuncAttributeMaxDynamicSharedMemorySize, SCAN_LDS);
  k_scan<<<128, 256, SCAN_LDS, stream>>>(w_P, w_eexp, w_start, w_ea, w_evp);
  k_final<<<1, 64, 0, stream>>>(w_evp, (float*)d_out);
}